// Round 1
// baseline (798.643 us; speedup 1.0000x reference)
//
#include <hip/hip_runtime.h>
#include <hip/hip_bf16.h>

#define S_SEQ 8192
#define D_DIM 1024
#define NCLS 7

typedef __bf16 bf16x8 __attribute__((ext_vector_type(8)));
typedef float f32x4 __attribute__((ext_vector_type(4)));

typedef const __attribute__((address_space(1))) void* gas_ptr;
typedef __attribute__((address_space(3))) void* las_ptr;
#define GLL(gp, lp) __builtin_amdgcn_global_load_lds((gas_ptr)(const void*)(gp), (las_ptr)(void*)(lp), 16, 0, 0)

__device__ __forceinline__ unsigned short f2bf(float f) {
    unsigned int u = __builtin_bit_cast(unsigned int, f);
    u = (u + 0x7FFFu + ((u >> 16) & 1u)) >> 16;
    return (unsigned short)u;
}

// ---------------- elementwise fp32 -> bf16 ----------------
__global__ __launch_bounds__(256) void k_f32_to_bf16(const float* __restrict__ src,
                                                     unsigned short* __restrict__ dst, int n4) {
    int i = blockIdx.x * 256 + threadIdx.x;
    if (i >= n4) return;
    float4 v = ((const float4*)src)[i];
    ushort4 o;
    o.x = f2bf(v.x); o.y = f2bf(v.y); o.z = f2bf(v.z); o.w = f2bf(v.w);
    ((ushort4*)dst)[i] = o;
}

// ---------------- transpose fp32 [R][C] -> bf16 [C][R] ----------------
__global__ __launch_bounds__(256) void k_transpose_f32_bf16(const float* __restrict__ src,
                                                            unsigned short* __restrict__ dst,
                                                            int R, int C) {
    __shared__ unsigned short t[64][80];
    int r0 = blockIdx.x * 64, c0 = blockIdx.y * 64;
    int tid = threadIdx.x;
    int rr = tid >> 4, cc = (tid & 15) << 2;
#pragma unroll
    for (int p = 0; p < 4; ++p) {
        int r = rr + p * 16;
        float4 v = *(const float4*)(src + (size_t)(r0 + r) * C + c0 + cc);
        t[cc + 0][r] = f2bf(v.x);
        t[cc + 1][r] = f2bf(v.y);
        t[cc + 2][r] = f2bf(v.z);
        t[cc + 3][r] = f2bf(v.w);
    }
    __syncthreads();
    int wr = tid >> 3, wc = (tid & 7) << 3;
#pragma unroll
    for (int p = 0; p < 2; ++p) {
        int c = wr + p * 32;
        uint4 v8 = *(const uint4*)&t[c][wc];
        *(uint4*)(dst + (size_t)(c0 + c) * R + r0 + wc) = v8;
    }
}

// ---------------- transpose bf16 [R][C] -> bf16 [C][R] ----------------
__global__ __launch_bounds__(256) void k_transpose_bf16(const unsigned short* __restrict__ src,
                                                        unsigned short* __restrict__ dst,
                                                        int R, int C) {
    __shared__ unsigned short t[64][80];
    int r0 = blockIdx.x * 64, c0 = blockIdx.y * 64;
    int tid = threadIdx.x;
    int rr = tid >> 3, cc = (tid & 7) << 3;
#pragma unroll
    for (int p = 0; p < 2; ++p) {
        int r = rr + p * 32;
        uint4 v = *(const uint4*)(src + (size_t)(r0 + r) * C + c0 + cc);
        const unsigned short* pv = (const unsigned short*)&v;
#pragma unroll
        for (int i = 0; i < 8; ++i) t[cc + i][r] = pv[i];
    }
    __syncthreads();
    int wr = tid >> 3, wc = (tid & 7) << 3;
#pragma unroll
    for (int p = 0; p < 2; ++p) {
        int c = wr + p * 32;
        uint4 v8 = *(const uint4*)&t[c][wc];
        *(uint4*)(dst + (size_t)(c0 + c) * R + r0 + wc) = v8;
    }
}

// ---------------- LayerNorm row kernel: bf16 out ----------------
__global__ __launch_bounds__(256) void k_ln_bf16(const float* __restrict__ Y,
                                                 const float* __restrict__ bias,
                                                 const float* __restrict__ g,
                                                 const float* __restrict__ beta,
                                                 unsigned short* __restrict__ out) {
    __shared__ float red[8];
    int row = blockIdx.x, tid = threadIdx.x;
    size_t off = (size_t)row * D_DIM + tid * 4;
    float4 y = *(const float4*)(Y + off);
    float4 b4 = *(const float4*)(bias + tid * 4);
    y.x += b4.x; y.y += b4.y; y.z += b4.z; y.w += b4.w;
    float s = y.x + y.y + y.z + y.w;
    float s2 = y.x * y.x + y.y * y.y + y.z * y.z + y.w * y.w;
#pragma unroll
    for (int o = 32; o; o >>= 1) { s += __shfl_down(s, o); s2 += __shfl_down(s2, o); }
    int lane = tid & 63, wv = tid >> 6;
    if (lane == 0) { red[wv] = s; red[4 + wv] = s2; }
    __syncthreads();
    s = red[0] + red[1] + red[2] + red[3];
    s2 = red[4] + red[5] + red[6] + red[7];
    float m = s * (1.0f / D_DIM);
    float var = s2 * (1.0f / D_DIM) - m * m;
    float rs = rsqrtf(var + 1e-5f);
    float4 g4 = *(const float4*)(g + tid * 4);
    float4 be4 = *(const float4*)(beta + tid * 4);
    ushort4 o4;
    o4.x = f2bf((y.x - m) * rs * g4.x + be4.x);
    o4.y = f2bf((y.y - m) * rs * g4.y + be4.y);
    o4.z = f2bf((y.z - m) * rs * g4.z + be4.z);
    o4.w = f2bf((y.w - m) * rs * g4.w + be4.w);
    *(ushort4*)(out + off) = o4;
}

// ---------------- row stats: max and 1/sum(exp) per 8192-wide row ----------------
__global__ __launch_bounds__(256) void k_row_stats(const float* __restrict__ A,
                                                   float* __restrict__ rmax,
                                                   float* __restrict__ rrecip) {
    __shared__ float red[8];
    int row = blockIdx.x, tid = threadIdx.x;
    const float4* p = (const float4*)(A + (size_t)row * S_SEQ);
    float4 v[8];
    float mx = -3.4e38f;
#pragma unroll
    for (int q = 0; q < 8; ++q) {
        v[q] = p[q * 256 + tid];
        mx = fmaxf(mx, fmaxf(fmaxf(v[q].x, v[q].y), fmaxf(v[q].z, v[q].w)));
    }
#pragma unroll
    for (int o = 32; o; o >>= 1) mx = fmaxf(mx, __shfl_down(mx, o));
    int lane = tid & 63, wv = tid >> 6;
    if (lane == 0) red[wv] = mx;
    __syncthreads();
    mx = fmaxf(fmaxf(red[0], red[1]), fmaxf(red[2], red[3]));
    float sum = 0.0f;
#pragma unroll
    for (int q = 0; q < 8; ++q) {
        sum += __expf(v[q].x - mx) + __expf(v[q].y - mx) + __expf(v[q].z - mx) + __expf(v[q].w - mx);
    }
#pragma unroll
    for (int o = 32; o; o >>= 1) sum += __shfl_down(sum, o);
    if (lane == 0) red[4 + wv] = sum;
    __syncthreads();
    if (tid == 0) {
        float tot = red[4] + red[5] + red[6] + red[7];
        rmax[row] = mx;
        rrecip[row] = 1.0f / tot;
    }
}

// ---------------- normalize (in-place fp32) + transposed bf16 copy ----------------
__global__ __launch_bounds__(256) void k_norm_transpose(float* __restrict__ A,
                                                        const float* __restrict__ rmax,
                                                        const float* __restrict__ rrecip,
                                                        unsigned short* __restrict__ At) {
    __shared__ unsigned short t[64][80];
    int t0 = blockIdx.x * 64, s0 = blockIdx.y * 64;
    int tid = threadIdx.x;
    int rr = tid >> 4, cc = (tid & 15) << 2;
#pragma unroll
    for (int p = 0; p < 4; ++p) {
        int r = rr + p * 16;
        float m = rmax[t0 + r], rc = rrecip[t0 + r];
        size_t off = (size_t)(t0 + r) * S_SEQ + s0 + cc;
        float4 v = *(const float4*)(A + off);
        v.x = __expf(v.x - m) * rc;
        v.y = __expf(v.y - m) * rc;
        v.z = __expf(v.z - m) * rc;
        v.w = __expf(v.w - m) * rc;
        *(float4*)(A + off) = v;
        t[cc + 0][r] = f2bf(v.x);
        t[cc + 1][r] = f2bf(v.y);
        t[cc + 2][r] = f2bf(v.z);
        t[cc + 3][r] = f2bf(v.w);
    }
    __syncthreads();
    int wr = tid >> 3, wc = (tid & 7) << 3;
#pragma unroll
    for (int p = 0; p < 2; ++p) {
        int c = wr + p * 32;
        uint4 v8 = *(const uint4*)&t[c][wc];
        *(uint4*)(At + (size_t)(s0 + c) * S_SEQ + t0 + wc) = v8;
    }
}

// ---------------- classifier: c = x @ Wc + bc ----------------
__global__ __launch_bounds__(256) void k_classifier(const float* __restrict__ x,
                                                    const float* __restrict__ Wc,
                                                    const float* __restrict__ bc,
                                                    float* __restrict__ outc) {
    __shared__ float red[4][NCLS];
    int row = blockIdx.x, tid = threadIdx.x;
    float4 xv = *(const float4*)(x + (size_t)row * D_DIM + tid * 4);
    const float* w0 = Wc + (size_t)(tid * 4) * NCLS;
    float acc[NCLS];
#pragma unroll
    for (int j = 0; j < NCLS; ++j)
        acc[j] = xv.x * w0[j] + xv.y * w0[NCLS + j] + xv.z * w0[2 * NCLS + j] + xv.w * w0[3 * NCLS + j];
#pragma unroll
    for (int j = 0; j < NCLS; ++j)
#pragma unroll
        for (int o = 32; o; o >>= 1) acc[j] += __shfl_down(acc[j], o);
    int lane = tid & 63, wv = tid >> 6;
    if (lane == 0) {
#pragma unroll
        for (int j = 0; j < NCLS; ++j) red[wv][j] = acc[j];
    }
    __syncthreads();
    if (tid < NCLS) {
        float s = red[0][tid] + red[1][tid] + red[2][tid] + red[3][tid];
        outc[(size_t)row * NCLS + tid] = s + bc[tid];
    }
}

// ---------------- bf16 GEMM: C[M,N] = scale * A[M,K] * B[N,K]^T (+bias[n]) ----------------
// m97-style: 128x128 tile, BK=32, 4 waves of 64x64, double-buffered LDS via global_load_lds.
__global__ __launch_bounds__(256) void k_gemm_bt(const unsigned short* __restrict__ A,
                                                 const unsigned short* __restrict__ B,
                                                 float* __restrict__ C,
                                                 int M, int N, int K,
                                                 float scale, const float* __restrict__ bias) {
    __shared__ unsigned short As[2][128 * 32];
    __shared__ unsigned short Bs[2][128 * 32];
    const int tid = threadIdx.x;
    const int lane = tid & 63;
    const int wid = tid >> 6;
    const int brow = blockIdx.x << 7;
    const int bcol = blockIdx.y << 7;
    const int wm = (wid >> 1) << 6;
    const int wn = (wid & 1) << 6;
    const int srow = lane >> 2;
    const int scol = (lane & 3) << 3;

    const unsigned short* gA0 = A + (size_t)(brow + wid * 32 + srow) * K + scol;
    const unsigned short* gA1 = gA0 + (size_t)16 * K;
    const unsigned short* gB0 = B + (size_t)(bcol + wid * 32 + srow) * K + scol;
    const unsigned short* gB1 = gB0 + (size_t)16 * K;
    unsigned short* lA0 = &As[0][(wid * 32) * 32];
    unsigned short* lA1 = &As[0][(wid * 32 + 16) * 32];
    unsigned short* lB0 = &Bs[0][(wid * 32) * 32];
    unsigned short* lB1 = &Bs[0][(wid * 32 + 16) * 32];
    const int bufstride = 128 * 32;

    f32x4 acc[4][4] = {};

    const int nt = K >> 5;
    GLL(gA0, lA0); GLL(gA1, lA1); GLL(gB0, lB0); GLL(gB1, lB1);
    __syncthreads();

    const int fm = lane & 15;
    const int kg = (lane >> 4) << 3;

    for (int t = 0; t < nt; ++t) {
        const int cur = t & 1;
        if (t + 1 < nt) {
            const size_t go = (size_t)(t + 1) << 5;
            const int lo = (cur ^ 1) * bufstride;
            GLL(gA0 + go, lA0 + lo);
            GLL(gA1 + go, lA1 + lo);
            GLL(gB0 + go, lB0 + lo);
            GLL(gB1 + go, lB1 + lo);
        }
        const unsigned short* as = &As[cur][0];
        const unsigned short* bs = &Bs[cur][0];
        bf16x8 af[4], bfv[4];
#pragma unroll
        for (int i = 0; i < 4; ++i)
            af[i] = *(const bf16x8*)(as + (wm + i * 16 + fm) * 32 + kg);
#pragma unroll
        for (int j = 0; j < 4; ++j)
            bfv[j] = *(const bf16x8*)(bs + (wn + j * 16 + fm) * 32 + kg);
#pragma unroll
        for (int i = 0; i < 4; ++i)
#pragma unroll
            for (int j = 0; j < 4; ++j)
                acc[i][j] = __builtin_amdgcn_mfma_f32_16x16x32_bf16(af[i], bfv[j], acc[i][j], 0, 0, 0);
        if (t + 1 < nt) __syncthreads();
    }

    const int r0 = (lane >> 4) << 2;
#pragma unroll
    for (int i = 0; i < 4; ++i) {
#pragma unroll
        for (int j = 0; j < 4; ++j) {
            int col = bcol + wn + j * 16 + fm;
            float badd = bias ? bias[col] : 0.0f;
#pragma unroll
            for (int r = 0; r < 4; ++r) {
                int row = brow + wm + i * 16 + r0 + r;
                C[(size_t)row * N + col] = acc[i][j][r] * scale + badd;
            }
        }
    }
}

extern "C" void kernel_launch(void* const* d_in, const int* in_sizes, int n_in,
                              void* d_out, int out_size, void* d_ws, size_t ws_size,
                              hipStream_t stream) {
    const float* x     = (const float*)d_in[0];
    const float* Wq    = (const float*)d_in[1];
    const float* bq    = (const float*)d_in[2];
    const float* gq    = (const float*)d_in[3];
    const float* betaq = (const float*)d_in[4];
    const float* Wk    = (const float*)d_in[5];
    const float* bk    = (const float*)d_in[6];
    const float* gk    = (const float*)d_in[7];
    const float* betak = (const float*)d_in[8];
    const float* Wv    = (const float*)d_in[9];
    const float* bv    = (const float*)d_in[10];
    const float* gv    = (const float*)d_in[11];
    const float* betav = (const float*)d_in[12];
    const float* Wo    = (const float*)d_in[13];
    const float* bo    = (const float*)d_in[14];
    const float* Wc    = (const float*)d_in[15];
    const float* bc    = (const float*)d_in[16];

    float* out_o    = (float*)d_out;
    float* out_c    = out_o + (size_t)S_SEQ * D_DIM;
    float* out_attn = out_c + (size_t)S_SEQ * NCLS;

    char* cur = (char*)d_ws;
    auto alloc = [&](size_t bytes) {
        char* p = cur;
        cur += (bytes + 255) & ~(size_t)255;
        return p;
    };
    const size_t SD2 = (size_t)S_SEQ * D_DIM * 2;
    const size_t DD2 = (size_t)D_DIM * D_DIM * 2;
    unsigned short* xb   = (unsigned short*)alloc(SD2);
    unsigned short* wtq  = (unsigned short*)alloc(DD2);
    unsigned short* wtk  = (unsigned short*)alloc(DD2);
    unsigned short* wtv  = (unsigned short*)alloc(DD2);
    unsigned short* wto  = (unsigned short*)alloc(DD2);
    unsigned short* qb   = (unsigned short*)alloc(SD2);
    unsigned short* kb   = (unsigned short*)alloc(SD2);
    unsigned short* vb   = (unsigned short*)alloc(SD2);
    unsigned short* Vt   = (unsigned short*)alloc(SD2);
    unsigned short* valb = (unsigned short*)alloc(SD2);
    float* rmax   = (float*)alloc((size_t)S_SEQ * 4);
    float* rrecip = (float*)alloc((size_t)S_SEQ * 4);
    unsigned short* At = (unsigned short*)alloc((size_t)S_SEQ * S_SEQ * 2);

    const int n4_xd = S_SEQ * D_DIM / 4;

    // x -> bf16
    k_f32_to_bf16<<<n4_xd / 256, 256, 0, stream>>>(x, xb, n4_xd);
    // weight transposes (fp32 [K][N] -> bf16 [N][K])
    k_transpose_f32_bf16<<<dim3(16, 16), 256, 0, stream>>>(Wq, wtq, D_DIM, D_DIM);
    k_transpose_f32_bf16<<<dim3(16, 16), 256, 0, stream>>>(Wk, wtk, D_DIM, D_DIM);
    k_transpose_f32_bf16<<<dim3(16, 16), 256, 0, stream>>>(Wv, wtv, D_DIM, D_DIM);
    k_transpose_f32_bf16<<<dim3(16, 16), 256, 0, stream>>>(Wo, wto, D_DIM, D_DIM);
    // classifier (independent)
    k_classifier<<<S_SEQ, 256, 0, stream>>>(x, Wc, bc, out_c);

    // q/k/v chains: GEMM (pre-LN into out_attn scratch) + LN -> bf16
    dim3 g_embed(S_SEQ / 128, D_DIM / 128);
    k_gemm_bt<<<g_embed, 256, 0, stream>>>(xb, wtq, out_attn, S_SEQ, D_DIM, D_DIM, 1.0f, nullptr);
    k_ln_bf16<<<S_SEQ, 256, 0, stream>>>(out_attn, bq, gq, betaq, qb);
    k_gemm_bt<<<g_embed, 256, 0, stream>>>(xb, wtk, out_attn, S_SEQ, D_DIM, D_DIM, 1.0f, nullptr);
    k_ln_bf16<<<S_SEQ, 256, 0, stream>>>(out_attn, bk, gk, betak, kb);
    k_gemm_bt<<<g_embed, 256, 0, stream>>>(xb, wtv, out_attn, S_SEQ, D_DIM, D_DIM, 1.0f, nullptr);
    k_ln_bf16<<<S_SEQ, 256, 0, stream>>>(out_attn, bv, gv, betav, vb);

    // V^T for the A^T V GEMM
    k_transpose_bf16<<<dim3(S_SEQ / 64, D_DIM / 64), 256, 0, stream>>>(vb, Vt, S_SEQ, D_DIM);

    // logits = q k^T / 32  -> out_attn
    dim3 g_qkt(S_SEQ / 128, S_SEQ / 128);
    k_gemm_bt<<<g_qkt, 256, 0, stream>>>(qb, kb, out_attn, S_SEQ, S_SEQ, D_DIM, 0.03125f, nullptr);

    // softmax: stats then normalize-in-place + transposed bf16 copy
    k_row_stats<<<S_SEQ, 256, 0, stream>>>(out_attn, rmax, rrecip);
    k_norm_transpose<<<dim3(S_SEQ / 64, S_SEQ / 64), 256, 0, stream>>>(out_attn, rmax, rrecip, At);

    // values = A^T V  (fp32 into out_o scratch), then bf16
    dim3 g_val(S_SEQ / 128, D_DIM / 128);
    k_gemm_bt<<<g_val, 256, 0, stream>>>(At, Vt, out_o, S_SEQ, D_DIM, S_SEQ, 1.0f, nullptr);
    k_f32_to_bf16<<<n4_xd / 256, 256, 0, stream>>>(out_o, valb, n4_xd);

    // o = values @ Wo + bo
    k_gemm_bt<<<g_val, 256, 0, stream>>>(valb, wto, out_o, S_SEQ, D_DIM, D_DIM, 1.0f, bo);
}

// Round 2
// 710.166 us; speedup vs baseline: 1.1246x; 1.1246x over previous
//
#include <hip/hip_runtime.h>
#include <hip/hip_bf16.h>

#define S_SEQ 8192
#define D_DIM 1024
#define NCLS 7

typedef __bf16 bf16x8 __attribute__((ext_vector_type(8)));
typedef float f32x4 __attribute__((ext_vector_type(4)));

typedef const __attribute__((address_space(1))) void* gas_ptr;
typedef __attribute__((address_space(3))) void* las_ptr;
#define GLL(gp, lp) __builtin_amdgcn_global_load_lds((gas_ptr)(const void*)(gp), (las_ptr)(void*)(lp), 16, 0, 0)

__device__ __forceinline__ unsigned short f2bf(float f) {
    unsigned int u = __builtin_bit_cast(unsigned int, f);
    u = (u + 0x7FFFu + ((u >> 16) & 1u)) >> 16;
    return (unsigned short)u;
}

// ---------------- elementwise fp32 -> bf16 ----------------
__global__ __launch_bounds__(256) void k_f32_to_bf16(const float* __restrict__ src,
                                                     unsigned short* __restrict__ dst, int n4) {
    int i = blockIdx.x * 256 + threadIdx.x;
    if (i >= n4) return;
    float4 v = ((const float4*)src)[i];
    ushort4 o;
    o.x = f2bf(v.x); o.y = f2bf(v.y); o.z = f2bf(v.z); o.w = f2bf(v.w);
    ((ushort4*)dst)[i] = o;
}

// ---------------- transpose fp32 [R][C] -> bf16 [C][R] ----------------
__global__ __launch_bounds__(256) void k_transpose_f32_bf16(const float* __restrict__ src,
                                                            unsigned short* __restrict__ dst,
                                                            int R, int C) {
    __shared__ unsigned short t[64][80];
    int r0 = blockIdx.x * 64, c0 = blockIdx.y * 64;
    int tid = threadIdx.x;
    int rr = tid >> 4, cc = (tid & 15) << 2;
#pragma unroll
    for (int p = 0; p < 4; ++p) {
        int r = rr + p * 16;
        float4 v = *(const float4*)(src + (size_t)(r0 + r) * C + c0 + cc);
        t[cc + 0][r] = f2bf(v.x);
        t[cc + 1][r] = f2bf(v.y);
        t[cc + 2][r] = f2bf(v.z);
        t[cc + 3][r] = f2bf(v.w);
    }
    __syncthreads();
    int wr = tid >> 3, wc = (tid & 7) << 3;
#pragma unroll
    for (int p = 0; p < 2; ++p) {
        int c = wr + p * 32;
        uint4 v8 = *(const uint4*)&t[c][wc];
        *(uint4*)(dst + (size_t)(c0 + c) * R + r0 + wc) = v8;
    }
}

// ---------------- transpose bf16 [R][C] -> bf16 [C][R] ----------------
__global__ __launch_bounds__(256) void k_transpose_bf16(const unsigned short* __restrict__ src,
                                                        unsigned short* __restrict__ dst,
                                                        int R, int C) {
    __shared__ unsigned short t[64][80];
    int r0 = blockIdx.x * 64, c0 = blockIdx.y * 64;
    int tid = threadIdx.x;
    int rr = tid >> 3, cc = (tid & 7) << 3;
#pragma unroll
    for (int p = 0; p < 2; ++p) {
        int r = rr + p * 32;
        uint4 v = *(const uint4*)(src + (size_t)(r0 + r) * C + c0 + cc);
        const unsigned short* pv = (const unsigned short*)&v;
#pragma unroll
        for (int i = 0; i < 8; ++i) t[cc + i][r] = pv[i];
    }
    __syncthreads();
    int wr = tid >> 3, wc = (tid & 7) << 3;
#pragma unroll
    for (int p = 0; p < 2; ++p) {
        int c = wr + p * 32;
        uint4 v8 = *(const uint4*)&t[c][wc];
        *(uint4*)(dst + (size_t)(c0 + c) * R + r0 + wc) = v8;
    }
}

// ---------------- LayerNorm row kernel (strided input): bf16 out ----------------
__global__ __launch_bounds__(256) void k_ln_bf16(const float* __restrict__ Y, int ldy,
                                                 const float* __restrict__ bias,
                                                 const float* __restrict__ g,
                                                 const float* __restrict__ beta,
                                                 unsigned short* __restrict__ out) {
    __shared__ float red[8];
    int row = blockIdx.x, tid = threadIdx.x;
    float4 y = *(const float4*)(Y + (size_t)row * ldy + tid * 4);
    float4 b4 = *(const float4*)(bias + tid * 4);
    y.x += b4.x; y.y += b4.y; y.z += b4.z; y.w += b4.w;
    float s = y.x + y.y + y.z + y.w;
    float s2 = y.x * y.x + y.y * y.y + y.z * y.z + y.w * y.w;
#pragma unroll
    for (int o = 32; o; o >>= 1) { s += __shfl_down(s, o); s2 += __shfl_down(s2, o); }
    int lane = tid & 63, wv = tid >> 6;
    if (lane == 0) { red[wv] = s; red[4 + wv] = s2; }
    __syncthreads();
    s = red[0] + red[1] + red[2] + red[3];
    s2 = red[4] + red[5] + red[6] + red[7];
    float m = s * (1.0f / D_DIM);
    float var = s2 * (1.0f / D_DIM) - m * m;
    float rs = rsqrtf(var + 1e-5f);
    float4 g4 = *(const float4*)(g + tid * 4);
    float4 be4 = *(const float4*)(beta + tid * 4);
    ushort4 o4;
    o4.x = f2bf((y.x - m) * rs * g4.x + be4.x);
    o4.y = f2bf((y.y - m) * rs * g4.y + be4.y);
    o4.z = f2bf((y.z - m) * rs * g4.z + be4.z);
    o4.w = f2bf((y.w - m) * rs * g4.w + be4.w);
    *(ushort4*)(out + (size_t)row * D_DIM + tid * 4) = o4;
}

// ---------------- row stats: max and 1/sum(exp) per 8192-wide row ----------------
__global__ __launch_bounds__(256) void k_row_stats(const float* __restrict__ A,
                                                   float* __restrict__ rmax,
                                                   float* __restrict__ rrecip) {
    __shared__ float red[8];
    int row = blockIdx.x, tid = threadIdx.x;
    const float4* p = (const float4*)(A + (size_t)row * S_SEQ);
    float4 v[8];
    float mx = -3.4e38f;
#pragma unroll
    for (int q = 0; q < 8; ++q) {
        v[q] = p[q * 256 + tid];
        mx = fmaxf(mx, fmaxf(fmaxf(v[q].x, v[q].y), fmaxf(v[q].z, v[q].w)));
    }
#pragma unroll
    for (int o = 32; o; o >>= 1) mx = fmaxf(mx, __shfl_down(mx, o));
    int lane = tid & 63, wv = tid >> 6;
    if (lane == 0) red[wv] = mx;
    __syncthreads();
    mx = fmaxf(fmaxf(red[0], red[1]), fmaxf(red[2], red[3]));
    float sum = 0.0f;
#pragma unroll
    for (int q = 0; q < 8; ++q) {
        sum += __expf(v[q].x - mx) + __expf(v[q].y - mx) + __expf(v[q].z - mx) + __expf(v[q].w - mx);
    }
#pragma unroll
    for (int o = 32; o; o >>= 1) sum += __shfl_down(sum, o);
    if (lane == 0) red[4 + wv] = sum;
    __syncthreads();
    if (tid == 0) {
        float tot = red[4] + red[5] + red[6] + red[7];
        rmax[row] = mx;
        rrecip[row] = 1.0f / tot;
    }
}

// ---------------- normalize (in-place fp32) + transposed bf16 copy ----------------
__global__ __launch_bounds__(256) void k_norm_transpose(float* __restrict__ A,
                                                        const float* __restrict__ rmax,
                                                        const float* __restrict__ rrecip,
                                                        unsigned short* __restrict__ At) {
    __shared__ unsigned short t[64][80];
    int t0 = blockIdx.x * 64, s0 = blockIdx.y * 64;
    int tid = threadIdx.x;
    int rr = tid >> 4, cc = (tid & 15) << 2;
#pragma unroll
    for (int p = 0; p < 4; ++p) {
        int r = rr + p * 16;
        float m = rmax[t0 + r], rc = rrecip[t0 + r];
        size_t off = (size_t)(t0 + r) * S_SEQ + s0 + cc;
        float4 v = *(const float4*)(A + off);
        v.x = __expf(v.x - m) * rc;
        v.y = __expf(v.y - m) * rc;
        v.z = __expf(v.z - m) * rc;
        v.w = __expf(v.w - m) * rc;
        *(float4*)(A + off) = v;
        t[cc + 0][r] = f2bf(v.x);
        t[cc + 1][r] = f2bf(v.y);
        t[cc + 2][r] = f2bf(v.z);
        t[cc + 3][r] = f2bf(v.w);
    }
    __syncthreads();
    int wr = tid >> 3, wc = (tid & 7) << 3;
#pragma unroll
    for (int p = 0; p < 2; ++p) {
        int c = wr + p * 32;
        uint4 v8 = *(const uint4*)&t[c][wc];
        *(uint4*)(At + (size_t)(s0 + c) * S_SEQ + t0 + wc) = v8;
    }
}

// ---------------- classifier: c = x @ Wc + bc ----------------
__global__ __launch_bounds__(256) void k_classifier(const float* __restrict__ x,
                                                    const float* __restrict__ Wc,
                                                    const float* __restrict__ bc,
                                                    float* __restrict__ outc) {
    __shared__ float red[4][NCLS];
    int row = blockIdx.x, tid = threadIdx.x;
    float4 xv = *(const float4*)(x + (size_t)row * D_DIM + tid * 4);
    const float* w0 = Wc + (size_t)(tid * 4) * NCLS;
    float acc[NCLS];
#pragma unroll
    for (int j = 0; j < NCLS; ++j)
        acc[j] = xv.x * w0[j] + xv.y * w0[NCLS + j] + xv.z * w0[2 * NCLS + j] + xv.w * w0[3 * NCLS + j];
#pragma unroll
    for (int j = 0; j < NCLS; ++j)
#pragma unroll
        for (int o = 32; o; o >>= 1) acc[j] += __shfl_down(acc[j], o);
    int lane = tid & 63, wv = tid >> 6;
    if (lane == 0) {
#pragma unroll
        for (int j = 0; j < NCLS; ++j) red[wv][j] = acc[j];
    }
    __syncthreads();
    if (tid < NCLS) {
        float s = red[0][tid] + red[1][tid] + red[2][tid] + red[3][tid];
        outc[(size_t)row * NCLS + tid] = s + bc[tid];
    }
}

// ============ pipelined bf16 GEMM: C[M,N] = scale*A[M,K]*B[N,K]^T (+bias) ============
// BM=256, BK=32, 512 threads (8 waves, WM x WN), 4 LDS buffers, 3-tiles-ahead
// prefetch with counted vmcnt (never 0 in steady state), LDS XOR swizzle applied
// via inverse-swizzled global source (global_load_lds writes linearly),
// setprio(1) around MFMA clusters, bijective XCD block swizzle.
// Requires: M%256==0, N%BN==0, K%32==0, K>=128, grid size % 8 == 0.
template<int BN, int WM, int WN>
__global__ __launch_bounds__(512) void k_gemm_big(const unsigned short* __restrict__ A,
                                                  const unsigned short* __restrict__ B,
                                                  float* __restrict__ C,
                                                  int M, int N, int K, float scale,
                                                  const float* __restrict__ bias) {
    constexpr int MREP = 256 / WM / 16;     // 8 (WM=2) or 4 (WM=4)
    constexpr int NREP = BN / WN / 16;      // 4
    constexpr int PHASES = MREP / 4;        // 2 or 1
    constexpr int BISS = BN / 128;          // B global_load_lds issues per K-tile
    constexpr int TISS = 2 + BISS;          // total issues per K-tile
    constexpr int ASLOT = 256 * 32;         // elements per A tile
    constexpr int BSLOT = BN * 32;
    constexpr int SLOT = ASLOT + BSLOT;
    __shared__ unsigned short lds[4 * SLOT];

    const int tid = threadIdx.x;
    const int lane = tid & 63;
    const int wid = tid >> 6;
    const int wm = wid / WN;
    const int wn = wid % WN;
    const int fm = lane & 15;
    const int g = lane >> 4;

    // bijective XCD swizzle (grid % 8 == 0)
    const int nbn = N / BN;
    const int nwg = gridDim.x;
    int bid = blockIdx.x;
    int wg = ((nwg & 7) == 0) ? ((bid & 7) * (nwg >> 3) + (bid >> 3)) : bid;
    const int bm = wg / nbn;
    const int bn = wg % nbn;
    const int brow = bm << 8;
    const int bcol = bn * BN;

    const int NT = K >> 5;

    // ----- staging (inverse-swizzled global source, linear LDS dest) -----
    const int arow = tid >> 2;                                   // 0..127
    const int scb = ((tid & 3) << 4) ^ ((arow & 6) << 3);        // swizzled col-byte
    const unsigned short* gA = A + (size_t)(brow + arow) * K + (scb >> 1);
    const unsigned short* gB = B + (size_t)(bcol + arow) * K + (scb >> 1);
    unsigned short* lA = lds + tid * 8;
    unsigned short* lB = lds + ASLOT + tid * 8;
    const size_t rows128A = (size_t)128 * K;

    auto stageA = [&](int kt, int slot) {
        const unsigned short* s = gA + ((size_t)kt << 5);
        unsigned short* d = lA + slot * SLOT;
        GLL(s, d);
        GLL(s + rows128A, d + 4096);
    };
    auto stageB = [&](int kt, int slot) {
        const unsigned short* s = gB + ((size_t)kt << 5);
        unsigned short* d = lB + slot * SLOT;
#pragma unroll
        for (int h = 0; h < BISS; ++h)
            GLL(s + (size_t)h * rows128A, d + h * 4096);
    };

    // ----- fragment read bases (swizzled) -----
    const int cbf = (((g << 4) ^ ((fm & 6) << 3)) >> 1);         // element offset in row
    const unsigned short* fA = lds + (wm * (256 / WM) + fm) * 32 + cbf;
    const unsigned short* fB = lds + ASLOT + (wn * (BN / WN) + fm) * 32 + cbf;

    f32x4 acc[MREP][NREP] = {};

    // prologue: stage tiles 0,1,2
    stageA(0, 0); stageB(0, 0);
    stageA(1, 1); stageB(1, 1);
    stageA(2, 2); stageB(2, 2);
    asm volatile("s_waitcnt vmcnt(%0)" :: "n"(2 * TISS) : "memory");  // tile 0 ready
    __builtin_amdgcn_s_barrier();

    for (int t = 0; t < NT; ++t) {
        const int slot = t & 3;
        const unsigned short* sA = fA + slot * SLOT;
        const unsigned short* sB = fB + slot * SLOT;
        const int pslot = (t + 3) & 3;
        const bool pf = (t + 3) < NT;

        bf16x8 bfr[NREP];
        bf16x8 afr[4];
        // ---- phase 1: A frags i=0..3 + all B frags ----
#pragma unroll
        for (int i = 0; i < 4; ++i) afr[i] = *(const bf16x8*)(sA + i * 512);
#pragma unroll
        for (int j = 0; j < NREP; ++j) bfr[j] = *(const bf16x8*)(sB + j * 512);
        if (pf) {
            stageA(t + 3, pslot);
            if (PHASES == 1) stageB(t + 3, pslot);
        }
        __builtin_amdgcn_s_barrier();
        asm volatile("s_waitcnt lgkmcnt(0)" ::: "memory");
        __builtin_amdgcn_s_setprio(1);
#pragma unroll
        for (int i = 0; i < 4; ++i)
#pragma unroll
            for (int j = 0; j < NREP; ++j)
                acc[i][j] = __builtin_amdgcn_mfma_f32_16x16x32_bf16(afr[i], bfr[j], acc[i][j], 0, 0, 0);
        __builtin_amdgcn_s_setprio(0);
        __builtin_amdgcn_s_barrier();

        if (PHASES == 2) {
            // ---- phase 2: A frags i=4..7, reuse B frags ----
#pragma unroll
            for (int i = 0; i < 4; ++i) afr[i] = *(const bf16x8*)(sA + (i + 4) * 512);
            if (pf) stageB(t + 3, pslot);
            __builtin_amdgcn_s_barrier();
            asm volatile("s_waitcnt lgkmcnt(0)" ::: "memory");
            __builtin_amdgcn_s_setprio(1);
#pragma unroll
            for (int i = 0; i < 4; ++i)
#pragma unroll
                for (int j = 0; j < NREP; ++j)
                    acc[(i + 4) % MREP][j] = __builtin_amdgcn_mfma_f32_16x16x32_bf16(afr[i], bfr[j], acc[(i + 4) % MREP][j], 0, 0, 0);
            __builtin_amdgcn_s_setprio(0);
        }

        // ---- counted wait: ensure tile t+1 resident before next iteration ----
        if (t + 1 < NT) {
            if (t + 3 < NT)
                asm volatile("s_waitcnt vmcnt(%0)" :: "n"(2 * TISS) : "memory");
            else if (t + 2 < NT)
                asm volatile("s_waitcnt vmcnt(%0)" :: "n"(TISS) : "memory");
            else
                asm volatile("s_waitcnt vmcnt(0)" ::: "memory");
        }
        __builtin_amdgcn_s_barrier();
    }

    // ---- epilogue ----
    const int r0 = g << 2;
#pragma unroll
    for (int i = 0; i < MREP; ++i) {
#pragma unroll
        for (int j = 0; j < NREP; ++j) {
            int col = bcol + wn * (BN / WN) + j * 16 + fm;
            float badd = bias ? bias[col] : 0.0f;
#pragma unroll
            for (int r = 0; r < 4; ++r) {
                int row = brow + wm * (256 / WM) + i * 16 + r0 + r;
                C[(size_t)row * N + col] = acc[i][j][r] * scale + badd;
            }
        }
    }
}

extern "C" void kernel_launch(void* const* d_in, const int* in_sizes, int n_in,
                              void* d_out, int out_size, void* d_ws, size_t ws_size,
                              hipStream_t stream) {
    const float* x     = (const float*)d_in[0];
    const float* Wq    = (const float*)d_in[1];
    const float* bq    = (const float*)d_in[2];
    const float* gq    = (const float*)d_in[3];
    const float* betaq = (const float*)d_in[4];
    const float* Wk    = (const float*)d_in[5];
    const float* bk    = (const float*)d_in[6];
    const float* gk    = (const float*)d_in[7];
    const float* betak = (const float*)d_in[8];
    const float* Wv    = (const float*)d_in[9];
    const float* bv    = (const float*)d_in[10];
    const float* gv    = (const float*)d_in[11];
    const float* betav = (const float*)d_in[12];
    const float* Wo    = (const float*)d_in[13];
    const float* bo    = (const float*)d_in[14];
    const float* Wc    = (const float*)d_in[15];
    const float* bc    = (const float*)d_in[16];

    float* out_o    = (float*)d_out;
    float* out_c    = out_o + (size_t)S_SEQ * D_DIM;
    float* out_attn = out_c + (size_t)S_SEQ * NCLS;

    char* cur = (char*)d_ws;
    auto alloc = [&](size_t bytes) {
        char* p = cur;
        cur += (bytes + 255) & ~(size_t)255;
        return p;
    };
    const size_t SD2 = (size_t)S_SEQ * D_DIM * 2;
    const size_t DD2 = (size_t)D_DIM * D_DIM * 2;
    unsigned short* xb   = (unsigned short*)alloc(SD2);
    unsigned short* wqkv = (unsigned short*)alloc(3 * DD2);   // [3072][1024] bf16
    unsigned short* wto  = (unsigned short*)alloc(DD2);
    unsigned short* qb   = (unsigned short*)alloc(SD2);
    unsigned short* kb   = (unsigned short*)alloc(SD2);
    unsigned short* vb   = (unsigned short*)alloc(SD2);
    unsigned short* Vt   = (unsigned short*)alloc(SD2);
    unsigned short* valb = (unsigned short*)alloc(SD2);
    float* rmax   = (float*)alloc((size_t)S_SEQ * 4);
    float* rrecip = (float*)alloc((size_t)S_SEQ * 4);
    unsigned short* At = (unsigned short*)alloc((size_t)S_SEQ * S_SEQ * 2);

    const int n4_xd = S_SEQ * D_DIM / 4;

    // x -> bf16
    k_f32_to_bf16<<<n4_xd / 256, 256, 0, stream>>>(x, xb, n4_xd);
    // weight transposes: fp32 [K][N] -> bf16 [N][K]; q/k/v concatenated along N
    k_transpose_f32_bf16<<<dim3(16, 16), 256, 0, stream>>>(Wq, wqkv, D_DIM, D_DIM);
    k_transpose_f32_bf16<<<dim3(16, 16), 256, 0, stream>>>(Wk, wqkv + (size_t)D_DIM * D_DIM, D_DIM, D_DIM);
    k_transpose_f32_bf16<<<dim3(16, 16), 256, 0, stream>>>(Wv, wqkv + (size_t)2 * D_DIM * D_DIM, D_DIM, D_DIM);
    k_transpose_f32_bf16<<<dim3(16, 16), 256, 0, stream>>>(Wo, wto, D_DIM, D_DIM);
    // classifier (independent)
    k_classifier<<<S_SEQ, 256, 0, stream>>>(x, Wc, bc, out_c);

    // fused QKV GEMM: [8192][3072] fp32 into out_attn scratch
    float* qkv = out_attn;
    k_gemm_big<128, 4, 2><<<(S_SEQ / 256) * (3 * D_DIM / 128), 512, 0, stream>>>(
        xb, wqkv, qkv, S_SEQ, 3 * D_DIM, D_DIM, 1.0f, nullptr);
    // per-chain LayerNorm -> bf16
    k_ln_bf16<<<S_SEQ, 256, 0, stream>>>(qkv,              3 * D_DIM, bq, gq, betaq, qb);
    k_ln_bf16<<<S_SEQ, 256, 0, stream>>>(qkv + D_DIM,      3 * D_DIM, bk, gk, betak, kb);
    k_ln_bf16<<<S_SEQ, 256, 0, stream>>>(qkv + 2 * D_DIM,  3 * D_DIM, bv, gv, betav, vb);

    // V^T for the A^T V GEMM
    k_transpose_bf16<<<dim3(S_SEQ / 64, D_DIM / 64), 256, 0, stream>>>(vb, Vt, S_SEQ, D_DIM);

    // logits = q k^T / 32  -> out_attn
    k_gemm_big<256, 2, 4><<<(S_SEQ / 256) * (S_SEQ / 256), 512, 0, stream>>>(
        qb, kb, out_attn, S_SEQ, S_SEQ, D_DIM, 0.03125f, nullptr);

    // softmax: stats then normalize-in-place + transposed bf16 copy
    k_row_stats<<<S_SEQ, 256, 0, stream>>>(out_attn, rmax, rrecip);
    k_norm_transpose<<<dim3(S_SEQ / 64, S_SEQ / 64), 256, 0, stream>>>(out_attn, rmax, rrecip, At);

    // values = A^T V  (fp32 into out_o scratch)
    k_gemm_big<128, 4, 2><<<(S_SEQ / 256) * (D_DIM / 128), 512, 0, stream>>>(
        At, Vt, out_o, S_SEQ, D_DIM, S_SEQ, 1.0f, nullptr);
    k_f32_to_bf16<<<n4_xd / 256, 256, 0, stream>>>(out_o, valb, n4_xd);

    // o = values @ Wo + bo
    k_gemm_big<128, 4, 2><<<(S_SEQ / 256) * (D_DIM / 128), 512, 0, stream>>>(
        valb, wto, out_o, S_SEQ, D_DIM, D_DIM, 1.0f, bo);
}